// Round 9
// baseline (250.237 us; speedup 1.0000x reference)
//
#include <hip/hip_runtime.h>

typedef __attribute__((ext_vector_type(2))) float f32x2;
typedef __attribute__((ext_vector_type(4))) float f32x4;
typedef __attribute__((ext_vector_type(8))) short s16x8;
typedef __attribute__((ext_vector_type(2))) unsigned int u32x2;
typedef __attribute__((ext_vector_type(4))) unsigned int u32x4;

#define BN 4
#define TN 4096
#define CN 120
#define HN 64

// RNE float->bf16 (finite inputs only)
__device__ __forceinline__ unsigned short f2bf(float f) {
  unsigned int u = __float_as_uint(f);
  unsigned int r = (u + 0x7fffu + ((u >> 16) & 1u)) >> 16;
  return (unsigned short)r;
}
__device__ __forceinline__ float fast_exp2(float x) {
#if __has_builtin(__builtin_amdgcn_exp2f)
  return __builtin_amdgcn_exp2f(x);
#else
  return exp2f(x);
#endif
}

// ---------------------------------------------------------------------------
// Kernel 1: projections, one matrix per block (grid 768 = 256 rowblocks x 3).
// Unchanged from round 8 (passing) EXCEPT the V epilogue now writes a
// key-tiled layout Vt2[b][kt=key/32][h][key%32] so attention's V staging is
// perfectly linear (round-8 lesson: wall time tracks divergent-request
// count; the old Vt rows forced 16-segment staging loads).
// ---------------------------------------------------------------------------
__global__ __launch_bounds__(256, 2) void proj_kernel(
    const float* __restrict__ x, const float* __restrict__ Wk,
    const float* __restrict__ Wq, const float* __restrict__ Wv,
    unsigned short* __restrict__ Kg, unsigned short* __restrict__ Qg,
    unsigned short* __restrict__ Vt2) {
  __shared__ struct {
    float w[CN][HN];              // fp32 W for this block's mat     30720 B
    union {
      float xr[64][124];          // fp32 x rows (pitch 124)         31744 B
      unsigned short vt[64][72];  // V transpose buffer               9216 B
    } u;
  } sm;
  const int tid = threadIdx.x;
  const int mat = blockIdx.x >> 8;  // 0=K 1=Q 2=V
  const int rb = blockIdx.x & 255;
  const int row0 = rb * 64;
  const float* Ws = (mat == 0) ? Wk : (mat == 1) ? Wq : Wv;
  {  // stage W fp32, coalesced f32x4
    const f32x4* s = (const f32x4*)Ws;
    f32x4* d = (f32x4*)&sm.w[0][0];
    for (int i = tid; i < CN * HN / 4; i += 256) d[i] = s[i];
  }
  // stage x fp32 (row pitch 124 floats)
  for (int n = tid; n < 64 * 30; n += 256) {
    const int row = n / 30, c4 = n - row * 30;
    *(f32x4*)&sm.u.xr[row][c4 * 4] =
        *(const f32x4*)&x[(size_t)(row0 + row) * CN + c4 * 4];
  }
  __syncthreads();
  const int hg = tid & 15;  // h = hg*4 .. +3
  const int rg = tid >> 4;  // rows rg*4 .. +3
  f32x4 acc[4];
#pragma unroll
  for (int r = 0; r < 4; ++r) acc[r] = 0.f;
  for (int c = 0; c < CN; c += 4) {
    f32x4 xv[4];
#pragma unroll
    for (int r = 0; r < 4; ++r) xv[r] = *(const f32x4*)&sm.u.xr[rg * 4 + r][c];
#pragma unroll
    for (int cc = 0; cc < 4; ++cc) {
      const f32x4 wv = *(const f32x4*)&sm.w[c + cc][hg * 4];
#pragma unroll
      for (int r = 0; r < 4; ++r) acc[r] += wv * xv[r][cc];
    }
  }
  if (mat < 2) {
    const float sc = (mat == 1) ? 0.13169944f : 1.0f;  // log2(e)/sqrt(120)
    unsigned short* dst = (mat == 1) ? Qg : Kg;
#pragma unroll
    for (int r = 0; r < 4; ++r) {
      u32x2 wd;
      wd.x = (unsigned int)f2bf(acc[r][0] * sc) |
             ((unsigned int)f2bf(acc[r][1] * sc) << 16);
      wd.y = (unsigned int)f2bf(acc[r][2] * sc) |
             ((unsigned int)f2bf(acc[r][3] * sc) << 16);
      *(u32x2*)&dst[(size_t)(row0 + rg * 4 + r) * HN + hg * 4] = wd;
    }
  } else {
    // V: transpose through LDS, then write tiled Vt2[b][kt][h][k32]
    __syncthreads();  // xr no longer needed (union reuse)
#pragma unroll
    for (int r = 0; r < 4; ++r)
#pragma unroll
      for (int j = 0; j < 4; ++j)
        sm.u.vt[hg * 4 + j][rg * 4 + r] = f2bf(acc[r][j]);
    __syncthreads();
    const int h = tid >> 2, ck = tid & 3;
    const int b = row0 >> 12, key0 = row0 & (TN - 1);
    const int kt = (key0 >> 5) + (ck >> 1);  // 32-key tile index
    unsigned short* vrow =
        Vt2 + ((size_t)((b * 128 + kt) * 64 + h)) * 32 + (ck & 1) * 16;
    const u32x4 d0 = *(const u32x4*)&sm.u.vt[h][ck * 16];
    const u32x4 d1 = *(const u32x4*)&sm.u.vt[h][ck * 16 + 8];
    *(u32x4*)vrow = d0;
    *(u32x4*)(vrow + 8) = d1;
  }
}

// ---------------------------------------------------------------------------
// Kernel 2: attention. Round-8 diagnosis: wall time == divergent-request
// count (16-row-strided frag loads = ~64 req/instr; ~109us of TA cycles).
// Fix: ALL global loads linear (lane L reads tile+L*16), K/V tiles staged in
// LDS via explicit u32x4 load + ds_write_b128 (NO global_load_lds: r5/r6's
// only unverified component; every mapping here is identity+pad, hand-
// checked). Double-buffered, ONE barrier/iter:
//   iter: ds_write g(tile it)->buf[it&1]; load g=tile it+1; barrier;
//         compute buf[it&1]
// (cross-wave write-vs-read of a buffer always separated by a barrier; the
// global load has a full compute phase to land before its ds_write waits.)
// Block = 32q, 4 waves = (ks,qs): ks halves keys (2048 each, 64x32-key
// tiles); qs0 stages K, qs1 stages V; all waves compute their (ks,qs) S/P/PV.
// LDS pads: K pitch 136B, V pitch 72B, P pitch 80B -> uniform bank depth
// (b128 floor). Math identical to r1/r8 (verified at 1.95e-3): exp2 on
// prescaled logits, clamp 80, l from truncated bf16 p, plain-sum merge.
// ---------------------------------------------------------------------------
__global__ __launch_bounds__(256, 4) void attn_kernel(
    const unsigned short* __restrict__ Qg, const unsigned short* __restrict__ Kg,
    const unsigned short* __restrict__ Vt2, float* __restrict__ out) {
  __shared__ unsigned char smem[40960];
  // layout: [ph][ks]: K tile 32x136B=4352, V tile 64x72B=4608 (8960/pair)
  //         phase stride 17920; P at 35840: wave*1280 + q*80
  const int bid = blockIdx.x;
  const int b = (bid & 7) >> 1;  // XCD swizzle: batch pinned to an XCD pair
  const int qt = (bid >> 3) | ((bid & 1) << 6);  // [0,128)
  const int qbase = qt * 32;
  const int tid = threadIdx.x;
  const int wave = tid >> 6, lane = tid & 63;
  const int ks = wave & 1, qs = wave >> 1;
  const int l15 = lane & 15, quad = lane >> 4;

  // Q B-operand frags: B[k=h][n=q]: q=l15, h=quad*8+j (+32)
  const unsigned short* qrow =
      Qg + (size_t)(b * TN + qbase + qs * 16 + l15) * HN + quad * 8;
  const s16x8 qf0 = *(const s16x8*)qrow;
  const s16x8 qf1 = *(const s16x8*)(qrow + 32);

  // ---- staging setup (all source reads linear: tile + j*1024 + lane*16) --
  const unsigned char* src =
      (qs == 0)
          ? (const unsigned char*)Kg + ((size_t)b * TN + ks * 2048) * 128 +
                lane * 16
          : (const unsigned char*)Vt2 + (size_t)(b * 128 + ks * 64) * 4096 +
                lane * 16;
  // LDS write offset for lane's 16B chunk, per j (identity layout + pad)
  int woff[4];
  const int wbase0 = ks * 8960 + (qs ? 4352 : 0);
#pragma unroll
  for (int j = 0; j < 4; ++j)
    woff[j] = (qs == 0)
                  ? wbase0 + (8 * j + (lane >> 3)) * 136 + (lane & 7) * 16
                  : wbase0 + (16 * j + (lane >> 2)) * 72 + (lane & 3) * 16;

  // compute-side LDS read offsets
  const int rbase = ks * 8960;
  int offK[2][2];
#pragma unroll
  for (int t = 0; t < 2; ++t)
#pragma unroll
    for (int fi = 0; fi < 2; ++fi)
      offK[t][fi] = rbase + (t * 16 + l15) * 136 + (quad + 4 * fi) * 16;
  int offV[4];
#pragma unroll
  for (int ht = 0; ht < 4; ++ht)
    offV[ht] = rbase + 4352 + (ht * 16 + l15) * 72 + quad * 16;
  unsigned char* const prow = smem + 35840 + wave * 1280 + l15 * 80;

  f32x4 o[4];
#pragma unroll
  for (int t = 0; t < 4; ++t) o[t] = 0.f;
  float lacc = 0.f;

  // prologue: load tile 0 into registers
  u32x4 g[4];
#pragma unroll
  for (int j = 0; j < 4; ++j) g[j] = *(const u32x4*)(src + j * 1024);

  for (int it = 0; it < 64; ++it) {
    const int ph = it & 1;
    unsigned char* const wb = smem + ph * 17920;
    // stage tile 'it' into buf[ph] (prev readers of buf[ph] are behind the
    // barrier of iter it-1)
#pragma unroll
    for (int j = 0; j < 4; ++j) *(u32x4*)(wb + woff[j]) = g[j];
    // issue next tile's loads (land during this iter's compute)
    if (it < 63) {
      const unsigned char* s2 = src + (size_t)(it + 1) * 4096;
#pragma unroll
      for (int j = 0; j < 4; ++j) g[j] = *(const u32x4*)(s2 + j * 1024);
    }
    __syncthreads();  // tile 'it' fully staged by all 4 waves
    const unsigned char* kk = smem + ph * 17920;
    // ---- S^T = K-tile * Q^T ----
    f32x4 s0 = 0.f, s1 = 0.f;
    {
      s16x8 a;
      a = *(const s16x8*)(kk + offK[0][0]);
      s0 = __builtin_amdgcn_mfma_f32_16x16x32_bf16(a, qf0, s0, 0, 0, 0);
      a = *(const s16x8*)(kk + offK[0][1]);
      s0 = __builtin_amdgcn_mfma_f32_16x16x32_bf16(a, qf1, s0, 0, 0, 0);
      a = *(const s16x8*)(kk + offK[1][0]);
      s1 = __builtin_amdgcn_mfma_f32_16x16x32_bf16(a, qf0, s1, 0, 0, 0);
      a = *(const s16x8*)(kk + offK[1][1]);
      s1 = __builtin_amdgcn_mfma_f32_16x16x32_bf16(a, qf1, s1, 0, 0, 0);
    }
    // ---- exp2, truncate to bf16, l from truncated values, store P^T ----
    // C/D layout: q=l15(col), key = 16t + quad*4 + reg
#pragma unroll
    for (int t = 0; t < 2; ++t) {
      const f32x4 s = t ? s1 : s0;
      unsigned int u0 = __float_as_uint(fast_exp2(fminf(s[0], 80.f)));
      unsigned int u1 = __float_as_uint(fast_exp2(fminf(s[1], 80.f)));
      unsigned int u2 = __float_as_uint(fast_exp2(fminf(s[2], 80.f)));
      unsigned int u3 = __float_as_uint(fast_exp2(fminf(s[3], 80.f)));
      u0 &= 0xffff0000u; u1 &= 0xffff0000u;
      u2 &= 0xffff0000u; u3 &= 0xffff0000u;
      lacc += (__uint_as_float(u0) + __uint_as_float(u1)) +
              (__uint_as_float(u2) + __uint_as_float(u3));
      u32x2 w;
      w.x = (u0 >> 16) | u1;
      w.y = (u2 >> 16) | u3;
      *(u32x2*)(prow + t * 32 + quad * 8) = w;  // keys 16t+quad*4..+3
    }
    // ---- O^T += V-tile * P^T (same-wave LDS RAW; compiler waits) ----
    const s16x8 pb = *(const s16x8*)(prow + quad * 16);
#pragma unroll
    for (int ht = 0; ht < 4; ++ht) {
      const s16x8 va = *(const s16x8*)(kk + offV[ht]);
      o[ht] = __builtin_amdgcn_mfma_f32_16x16x32_bf16(va, pb, o[ht], 0, 0, 0);
    }
  }
  // reduce l across quads (lane's column q=l15 fixed across quads)
  lacc += __shfl_xor(lacc, 16, 64);
  lacc += __shfl_xor(lacc, 32, 64);
  __syncthreads();  // all waves done reading smem tiles before reuse
  // epilogue arena: ob[w][q][h] pitch 68 floats at 0; lb at 17408
  float* const ob = (float*)smem;
  float* const lb = (float*)(smem + 17408);
  if (lane < 16) lb[wave * 16 + l15] = lacc;
#pragma unroll
  for (int ht = 0; ht < 4; ++ht)
    *(f32x4*)&ob[(wave * 16 + l15) * 68 + ht * 16 + quad * 4] = o[ht];
  __syncthreads();
  // merge the 2 ks partials per qs, normalize, coalesced store
  {
    const int q = tid >> 3, hc = tid & 7;       // q 0..31, h chunk 0..7
    const int q16 = q & 15, w0 = (q >> 4) * 2;  // waves {qs*2, qs*2+1}
    const float inv = 1.0f / (lb[w0 * 16 + q16] + lb[(w0 + 1) * 16 + q16]);
    const float* o0 = &ob[(w0 * 16 + q16) * 68];
    const float* o1 = &ob[((w0 + 1) * 16 + q16) * 68];
    f32x4 r0, r1;
#pragma unroll
    for (int j = 0; j < 4; ++j) {
      r0[j] = (o0[hc * 8 + j] + o1[hc * 8 + j]) * inv;
      r1[j] = (o0[hc * 8 + 4 + j] + o1[hc * 8 + 4 + j]) * inv;
    }
    float* op = out + (size_t)(b * TN + qbase + q) * HN + hc * 8;
    *(f32x4*)op = r0;
    *(f32x4*)(op + 4) = r1;
  }
}

extern "C" void kernel_launch(void* const* d_in, const int* in_sizes, int n_in,
                              void* d_out, int out_size, void* d_ws,
                              size_t ws_size, hipStream_t stream) {
  const float* x = (const float*)d_in[0];
  const float* Wk = (const float*)d_in[1];
  const float* Wq = (const float*)d_in[2];
  const float* Wv = (const float*)d_in[3];
  unsigned short* Kg = (unsigned short*)d_ws;             // [B*T][64] bf16
  unsigned short* Qg = Kg + (size_t)BN * TN * HN;         // [B*T][64] bf16
  unsigned short* Vt2 = Qg + (size_t)BN * TN * HN;        // [B][128][64][32]
  float* out = (float*)d_out;
  proj_kernel<<<768, 256, 0, stream>>>(x, Wk, Wq, Wv, Kg, Qg, Vt2);
  attn_kernel<<<512, 256, 0, stream>>>(Qg, Kg, Vt2, out);
}

// Round 10
// 124.324 us; speedup vs baseline: 2.0128x; 2.0128x over previous
//
#include <hip/hip_runtime.h>

typedef __attribute__((ext_vector_type(2))) float f32x2;
typedef __attribute__((ext_vector_type(4))) float f32x4;
typedef __attribute__((ext_vector_type(8))) short s16x8;
typedef __attribute__((ext_vector_type(2))) unsigned int u32x2;
typedef __attribute__((ext_vector_type(4))) unsigned int u32x4;

#define BN 4
#define TN 4096
#define CN 120
#define HN 64

// RNE float->bf16 (finite inputs only)
__device__ __forceinline__ unsigned short f2bf(float f) {
  unsigned int u = __float_as_uint(f);
  unsigned int r = (u + 0x7fffu + ((u >> 16) & 1u)) >> 16;
  return (unsigned short)r;
}
__device__ __forceinline__ float fast_exp2(float x) {
#if __has_builtin(__builtin_amdgcn_exp2f)
  return __builtin_amdgcn_exp2f(x);
#else
  return exp2f(x);
#endif
}

// ---------------------------------------------------------------------------
// Workspace layouts (round-10): K and V are stored PRE-PERMUTED into MFMA
// fragment order so every in-loop global load in attn is base + lane*16
// (1 segment/instr; round-8 diagnosis: 16-row-strided frag loads = ~16
// segments/instr saturate the TA at ~123us regardless of occupancy).
//   Kf[b][kt]   : kt = key/16, 2KB tile. chunk0 byte L*16 (L=lane 0..63) =
//                 K[b][kt*16 + (L&15)][h=(L>>4)*8 .. +8); chunk1 (+1024B) =
//                 same rows, h+32. (A-frag for S^T = K*Q^T.)
//   Qg[b*T+t][64] rows (bf16, pre-scaled by log2(e)/sqrt(120)) - loaded once
//                 per wave, strided is fine.
//   Vf[b][kb32][ht]: kb32 = key/32, ht = h/16 (0..3), 1KB: byte L*16 =
//                 V[b][h=ht*16+(L&15)][kb32*32 + (L>>4)*8 .. +8). (A-frag
//                 for O^T = V*P^T.)
// ---------------------------------------------------------------------------

// ---------------------------------------------------------------------------
// Kernel 1: projections, one matrix per block (grid 768 = 256 rowblocks x 3).
// W fp32 + 64 x rows fp32 in LDS (61KB, 2 blocks/CU); inner loop pure
// LDS+FMA (verified numerics: fp32 W, fp32 accum, RNE bf16 out).
// K and V epilogues transpose through LDS then emit the fragment-ordered
// tiles above with fully-coalesced 16B chunk writes.
// ---------------------------------------------------------------------------
__global__ __launch_bounds__(256, 2) void proj_kernel(
    const float* __restrict__ x, const float* __restrict__ Wk,
    const float* __restrict__ Wq, const float* __restrict__ Wv,
    unsigned short* __restrict__ Kf, unsigned short* __restrict__ Qg,
    unsigned short* __restrict__ Vf) {
  __shared__ struct {
    float w[CN][HN];              // fp32 W for this block's mat     30720 B
    union {
      float xr[64][124];          // fp32 x rows (pitch 124)         31744 B
      unsigned short vt[64][72];  // transpose buffer (pitch 72)      9216 B
    } u;
  } sm;
  const int tid = threadIdx.x;
  const int mat = blockIdx.x >> 8;  // 0=K 1=Q 2=V
  const int rb = blockIdx.x & 255;
  const int row0 = rb * 64;
  const float* Ws = (mat == 0) ? Wk : (mat == 1) ? Wq : Wv;
  {  // stage W fp32, coalesced f32x4
    const f32x4* s = (const f32x4*)Ws;
    f32x4* d = (f32x4*)&sm.w[0][0];
    for (int i = tid; i < CN * HN / 4; i += 256) d[i] = s[i];
  }
  // stage x fp32 (row pitch 124 floats)
  for (int n = tid; n < 64 * 30; n += 256) {
    const int row = n / 30, c4 = n - row * 30;
    *(f32x4*)&sm.u.xr[row][c4 * 4] =
        *(const f32x4*)&x[(size_t)(row0 + row) * CN + c4 * 4];
  }
  __syncthreads();
  const int hg = tid & 15;  // h = hg*4 .. +3
  const int rg = tid >> 4;  // rows rg*4 .. +3
  f32x4 acc[4];
#pragma unroll
  for (int r = 0; r < 4; ++r) acc[r] = 0.f;
  for (int c = 0; c < CN; c += 4) {
    f32x4 xv[4];
#pragma unroll
    for (int r = 0; r < 4; ++r) xv[r] = *(const f32x4*)&sm.u.xr[rg * 4 + r][c];
#pragma unroll
    for (int cc = 0; cc < 4; ++cc) {
      const f32x4 wv = *(const f32x4*)&sm.w[c + cc][hg * 4];
#pragma unroll
      for (int r = 0; r < 4; ++r) acc[r] += wv * xv[r][cc];
    }
  }
  const int b = row0 >> 12, key0 = row0 & (TN - 1);
  if (mat == 1) {
    // Q: plain rows, pre-scaled by log2(e)/sqrt(120)
    const float sc = 0.13169944f;
#pragma unroll
    for (int r = 0; r < 4; ++r) {
      u32x2 wd;
      wd.x = (unsigned int)f2bf(acc[r][0] * sc) |
             ((unsigned int)f2bf(acc[r][1] * sc) << 16);
      wd.y = (unsigned int)f2bf(acc[r][2] * sc) |
             ((unsigned int)f2bf(acc[r][3] * sc) << 16);
      *(u32x2*)&Qg[(size_t)(row0 + rg * 4 + r) * HN + hg * 4] = wd;
    }
  } else if (mat == 0) {
    // K: store [key][h] rows in LDS, then emit frag-ordered Kf tiles
    __syncthreads();  // xr dead (union reuse)
#pragma unroll
    for (int r = 0; r < 4; ++r) {
      u32x2 wd;
      wd.x = (unsigned int)f2bf(acc[r][0]) |
             ((unsigned int)f2bf(acc[r][1]) << 16);
      wd.y = (unsigned int)f2bf(acc[r][2]) |
             ((unsigned int)f2bf(acc[r][3]) << 16);
      *(u32x2*)&sm.u.vt[rg * 4 + r][hg * 4] = wd;
    }
    __syncthreads();
#pragma unroll
    for (int i = 0; i < 2; ++i) {
      const int c = tid + i * 256;          // 512 chunks: 4 kt x 2 ch x 64 L
      const int ktl = c >> 7, ch = (c >> 6) & 1, L = c & 63;
      const u32x4 d =
          *(const u32x4*)&sm.u.vt[ktl * 16 + (L & 15)][(L >> 4) * 8 + ch * 32];
      *(u32x4*)((unsigned char*)Kf +
                (((size_t)b * 256 + (key0 >> 4) + ktl) * 128 + ch * 64 + L) *
                    16) = d;
    }
  } else {
    // V: store [h][key] in LDS, then emit frag-ordered Vf tiles
    __syncthreads();  // xr dead (union reuse)
#pragma unroll
    for (int r = 0; r < 4; ++r)
#pragma unroll
      for (int j = 0; j < 4; ++j)
        sm.u.vt[hg * 4 + j][rg * 4 + r] = f2bf(acc[r][j]);
    __syncthreads();
#pragma unroll
    for (int i = 0; i < 2; ++i) {
      const int c = tid + i * 256;          // 512 chunks: 2 kb32 x 4 ht x 64 L
      const int kbl = c >> 8, ht = (c >> 6) & 3, L = c & 63;
      const u32x4 d =
          *(const u32x4*)&sm.u.vt[ht * 16 + (L & 15)][kbl * 32 + (L >> 4) * 8];
      *(u32x4*)((unsigned char*)Vf +
                (((size_t)b * 128 + (key0 >> 5) + kbl) * 4 + ht) * 1024 +
                L * 16) = d;
    }
  }
}

// ---------------------------------------------------------------------------
// Kernel 2: attention — round-8 kernel (VERIFIED: passed at 1.95e-3)
// byte-for-byte except the K/V load ADDRESSES now index the fragment-ordered
// Kf/Vf tiles: every in-loop load is base + lane*16 (coalesced, 1 segment,
// 1KB/instr) instead of 16-row-strided (~16 segments). Same values land in
// the same lanes -> bit-identical output. No LDS staging, no in-loop
// barriers (round-9's barrier/iter structure regressed to 170us).
// 16q/block, 8 waves, 8-way key split (512 keys/wave), plain-sum merge.
// ---------------------------------------------------------------------------
__global__ __launch_bounds__(512, 4) void attn_kernel(
    const unsigned short* __restrict__ Qg, const unsigned short* __restrict__ Kf,
    const unsigned short* __restrict__ Vf, float* __restrict__ out) {
  __shared__ union {
    unsigned short p[8][16][72];                         // 18432 B
    struct { float ob[8][64][17]; float lb[8][16]; } m;  // 35328 B
  } sm;
  const int bid = blockIdx.x;
  const int xslot = bid & 7;                 // XCD-aware swizzle:
  const int b = xslot >> 1;                  // batch pinned to an XCD pair
  const int qt = (bid >> 3) | ((xslot & 1) << 7);  // [0,256)
  const int qbase = qt * 16;
  const int tid = threadIdx.x;
  const int wave = tid >> 6, lane = tid & 63;
  const int l15 = lane & 15, quad = lane >> 4;

  // Q B-operand frags: B[k=h][n=q]: q = lane&15, h = quad*8+j (+32)
  const unsigned short* qrow =
      Qg + (size_t)(b * TN + qbase + l15) * HN + quad * 8;
  const s16x8 qf0 = *(const s16x8*)qrow;
  const s16x8 qf1 = *(const s16x8*)(qrow + 32);

  const unsigned char* Kfb = (const unsigned char*)Kf + (size_t)b * 524288;
  const unsigned char* Vfb = (const unsigned char*)Vf + (size_t)b * 524288;
  char* const pw = (char*)&sm.p[wave][0][0] + l15 * 144;  // write row q=l15
  char* const pr = (char*)&sm.p[wave][0][0] + l15 * 144 + quad * 16;

  f32x4 o[4];
#pragma unroll
  for (int t = 0; t < 4; ++t) o[t] = 0.f;
  float lacc = 0.f;

  const int kb0 = wave * 512;  // 8-way key split, 512 keys/wave
#pragma unroll 1
  for (int it = 0; it < 8; ++it) {
    const int kb = kb0 + it * 64;
    // ---- S^T = K-tile * Q^T (frag loads: base + lane*16, coalesced) ----
    f32x4 s[4];
#pragma unroll
    for (int t = 0; t < 4; ++t) {
      const unsigned char* ktp =
          Kfb + (size_t)((kb >> 4) + t) * 2048 + lane * 16;
      const s16x8 a0 = *(const s16x8*)ktp;
      const s16x8 a1 = *(const s16x8*)(ktp + 1024);
      s[t] = 0.f;
      s[t] = __builtin_amdgcn_mfma_f32_16x16x32_bf16(a0, qf0, s[t], 0, 0, 0);
      s[t] = __builtin_amdgcn_mfma_f32_16x16x32_bf16(a1, qf1, s[t], 0, 0, 0);
    }
    // ---- exp2, truncate to bf16, l from truncated values, store P^T ----
    // S^T C/D layout: q=l15(col), key = 16t + quad*4 + reg
#pragma unroll
    for (int t = 0; t < 4; ++t) {
      unsigned int u0 = __float_as_uint(fast_exp2(fminf(s[t][0], 80.f)));
      unsigned int u1 = __float_as_uint(fast_exp2(fminf(s[t][1], 80.f)));
      unsigned int u2 = __float_as_uint(fast_exp2(fminf(s[t][2], 80.f)));
      unsigned int u3 = __float_as_uint(fast_exp2(fminf(s[t][3], 80.f)));
      u0 &= 0xffff0000u; u1 &= 0xffff0000u;
      u2 &= 0xffff0000u; u3 &= 0xffff0000u;
      lacc += (__uint_as_float(u0) + __uint_as_float(u1)) +
              (__uint_as_float(u2) + __uint_as_float(u3));
      u32x2 w;
      w.x = (u0 >> 16) | u1;
      w.y = (u2 >> 16) | u3;
      *(u32x2*)(pw + t * 32 + quad * 8) = w;  // keys 16t+quad*4 .. +3
    }
    // ---- O^T += V * P^T (same-wave LDS RAW: DS ops complete in order) ----
#pragma unroll
    for (int kc = 0; kc < 2; ++kc) {
      // B-operand: B[k=key][n=q]: row q=l15, key bytes quad*16 + kc*64
      const s16x8 pb = *(const s16x8*)(pr + kc * 64);
#pragma unroll
      for (int ht = 0; ht < 4; ++ht) {
        const unsigned char* vtp =
            Vfb + (size_t)((kb >> 5) + kc) * 4096 + ht * 1024 + lane * 16;
        const s16x8 va = *(const s16x8*)vtp;
        o[ht] = __builtin_amdgcn_mfma_f32_16x16x32_bf16(va, pb, o[ht], 0, 0, 0);
      }
    }
  }
  // l currently partial per lane (its own keys); reduce across quads
  lacc += __shfl_xor(lacc, 16, 64);
  lacc += __shfl_xor(lacc, 32, 64);
  __syncthreads();  // all waves done with sm.p before union reuse
  if (lane < 16) sm.m.lb[wave][l15] = lacc;
#pragma unroll
  for (int ht = 0; ht < 4; ++ht)
#pragma unroll
    for (int r = 0; r < 4; ++r)
      sm.m.ob[wave][ht * 16 + quad * 4 + r][l15] = o[ht][r];
  __syncthreads();
  // merge 8 key-split partials, normalize, coalesced store
  const int h = tid & 63;
  const int wq = tid >> 6;  // 0..7
#pragma unroll
  for (int i = 0; i < 2; ++i) {
    const int qq = (i << 3) | wq;  // 0..15
    float ssum = 0.f, ll = 0.f;
#pragma unroll
    for (int w = 0; w < 8; ++w) {
      ssum += sm.m.ob[w][h][qq];
      ll += sm.m.lb[w][qq];
    }
    out[(size_t)(b * TN + qbase + qq) * HN + h] = ssum / ll;
  }
}

extern "C" void kernel_launch(void* const* d_in, const int* in_sizes, int n_in,
                              void* d_out, int out_size, void* d_ws,
                              size_t ws_size, hipStream_t stream) {
  const float* x = (const float*)d_in[0];
  const float* Wk = (const float*)d_in[1];
  const float* Wq = (const float*)d_in[2];
  const float* Wv = (const float*)d_in[3];
  unsigned short* Kf = (unsigned short*)d_ws;             // [B][256] 2KB tiles
  unsigned short* Qg = Kf + (size_t)BN * TN * HN;         // [B*T][64] rows
  unsigned short* Vf = Qg + (size_t)BN * TN * HN;         // [B][128][4] 1KB
  float* out = (float*)d_out;
  proj_kernel<<<768, 256, 0, stream>>>(x, Wk, Wq, Wv, Kf, Qg, Vf);
  attn_kernel<<<BN * TN / 16, 512, 0, stream>>>(Qg, Kf, Vf, out);
}